// Round 5
// baseline (999.655 us; speedup 1.0000x reference)
//
#include <hip/hip_runtime.h>

// SingleLSTM: B=32768, T=28, INPUT=28, HIDDEN=128, LABELS=10, fp32.
// R5: fp16 datapath; 32 rows/block, 1024 blocks, launch_bounds(512,4)
// -> <=128 VGPRs -> 4 waves/SIMD -> 2 resident blocks/CU (out-of-phase
// blocks overlap MFMA and VALU pipes). Register diet: Wx in LDS (B-frag
// transposed layout), acc processed one 16-row tile at a time (16 regs),
// x staged via LDS pre-converted. W/bias pre-scaled by {-L2E, 2L2E, -L2E,
// -L2E}; c kept in 2*L2E units -> activation is pure exp2/rcp/fma.

typedef _Float16 f16x8 __attribute__((ext_vector_type(8)));
typedef float f32x4 __attribute__((ext_vector_type(4)));

#define HSTRIDE 136    // f16 elems; 272B row -> uniform-depth LDS access
#define WXSTRIDE 40    // f16 elems; 80B row -> b128 starts tile all banks
#define L2E 1.44269504f

__global__ __launch_bounds__(512, 4)
void lstm_r5(const float* __restrict__ x,      // [B][28][28]
             const float* __restrict__ W,      // [156][512]
             const float* __restrict__ b,      // [512]
             const float* __restrict__ Wfc,    // [128][10]
             const float* __restrict__ bfc,    // [10]
             float* __restrict__ out)          // [B][10]
{
    __shared__ __align__(16) _Float16 h_s[2][32 * HSTRIDE];
    __shared__ __align__(16) _Float16 xs[2][2][512];        // [buf][mt][kb*128+r*8+kk]
    __shared__ __align__(16) _Float16 wxt[512 * WXSTRIDE];  // [col][k], k<28 (28..31 zero)

    const int tid  = threadIdx.x;
    const int wave = tid >> 6;
    const int lane = tid & 63;
    const int m16  = lane & 15;
    const int quad = lane >> 4;
    const int rbase = blockIdx.x * 32;
    const int hc = wave * 16 + m16;     // this lane's hidden column

    // ---- zero h buf0 and xs (k>=28 slots must stay 0) ----
    for (int i = tid; i < 32 * HSTRIDE; i += 512) h_s[0][i] = (_Float16)0.0f;
    for (int i = tid; i < 2 * 2 * 512; i += 512) ((_Float16*)xs)[i] = (_Float16)0.0f;

    // ---- stage Wx into LDS, transposed [col][k], pre-scaled ----
    {
        const int col = tid;                 // 512 cols, one per thread
        const int g = col >> 7;
        const float sc = (g == 1) ? 2.0f * L2E : -L2E;
        #pragma unroll 4
        for (int k = 0; k < 32; k++)
            wxt[col * WXSTRIDE + k] = (k < 28) ? (_Float16)(sc * W[k * 512 + col])
                                               : (_Float16)0.0f;
    }

    // ---- Wh fragments (fp16, pre-scaled), B-layout: lane holds B[k=quad*8+j][col]
    f16x8 Wh[4][4];     // [ks][gate]
    float bias[4];
    #pragma unroll
    for (int g = 0; g < 4; g++) {
        const int col = g * 128 + wave * 16 + m16;
        const float sc = (g == 1) ? 2.0f * L2E : -L2E;
        bias[g] = sc * (b[col] + (g == 2 ? 1.0f : 0.0f));   // FORGET_BIAS folded
        #pragma unroll
        for (int ks = 0; ks < 4; ks++) {
            f16x8 h8;
            #pragma unroll
            for (int j = 0; j < 8; j++)
                h8[j] = (_Float16)(sc * W[(28 + ks * 32 + quad * 8 + j) * 512 + col]);
            Wh[ks][g] = h8;
        }
    }

    // ---- per-thread x staging slots (32 rows x 28 k = 896 elems) ----
    const int srow  = tid / 28, sk  = tid % 28;
    const int smt   = srow >> 4;
    const int soff  = (sk >> 3) * 128 + (srow & 15) * 8 + (sk & 7);
    const int sidx2 = tid + 512;
    const int srow2 = sidx2 / 28, sk2 = sidx2 % 28;
    const int smt2  = srow2 >> 4;
    const int soff2 = (sk2 >> 3) * 128 + (srow2 & 15) * 8 + (sk2 & 7);
    const float* xp  = x + (size_t)(rbase + srow)  * 784 + sk;
    const float* xp2 = x + (size_t)(rbase + srow2) * 784 + sk2;

    // stage x for t=0
    xs[0][smt][soff] = (_Float16)(*xp);
    if (tid < 384) xs[0][smt2][soff2] = (_Float16)(*xp2);
    __syncthreads();

    float creg[8];
    #pragma unroll
    for (int i = 0; i < 8; i++) creg[i] = 0.0f;

    const int foff   = quad * 128 + m16 * 8;                 // xs A-frag offset
    const int wxoff0 = (wave * 16 + m16) * WXSTRIDE + quad * 8;

    int buf = 0;
    for (int t = 0; t < 28; t++) {
        const int nb = buf ^ 1;

        // stage x for t+1 (latency hidden under MFMAs)
        if (t < 27) {
            xs[nb][smt][soff] = (_Float16)(xp[(t + 1) * 28]);
            if (tid < 384) xs[nb][smt2][soff2] = (_Float16)(xp2[(t + 1) * 28]);
        }

        #pragma unroll
        for (int mt = 0; mt < 2; mt++) {
            // gates for 16 rows: acc[g][r], row = mt*16 + quad*4 + r, col = hc
            f32x4 acc[4];
            #pragma unroll
            for (int g = 0; g < 4; g++)
                acc[g] = (f32x4){bias[g], bias[g], bias[g], bias[g]};

            f16x8 ax = *(const f16x8*)(&xs[buf][mt][foff]);
            #pragma unroll
            for (int g = 0; g < 4; g++) {
                f16x8 wxf = *(const f16x8*)(&wxt[g * 128 * WXSTRIDE + wxoff0]);
                acc[g] = __builtin_amdgcn_mfma_f32_16x16x32_f16(ax, wxf, acc[g], 0, 0, 0);
            }
            #pragma unroll
            for (int ks = 0; ks < 4; ks++) {
                f16x8 ah = *(const f16x8*)(&h_s[buf][(mt * 16 + m16) * HSTRIDE + ks * 32 + quad * 8]);
                #pragma unroll
                for (int g = 0; g < 4; g++)
                    acc[g] = __builtin_amdgcn_mfma_f32_16x16x32_f16(ah, Wh[ks][g], acc[g], 0, 0, 0);
            }

            // per-lane c/h update (gates pre-scaled: i,f,o by -L2E; j by 2L2E)
            #pragma unroll
            for (int r = 0; r < 4; r++) {
                float ei  = __builtin_amdgcn_exp2f(acc[0][r]);   // e^-i
                float e2j = __builtin_amdgcn_exp2f(acc[1][r]);   // e^2j
                float ef  = __builtin_amdgcn_exp2f(acc[2][r]);   // e^-(f+1)
                float eo  = __builtin_amdgcn_exp2f(acc[3][r]);   // e^-o
                float r1  = __builtin_amdgcn_rcpf((1.0f + ei) * (e2j + 1.0f));
                float num = __builtin_fmaf(e2j, 2.0f * L2E, -2.0f * L2E);
                float sf  = __builtin_amdgcn_rcpf(1.0f + ef);
                float cn  = __builtin_fmaf(creg[mt * 4 + r], sf, num * r1);  // c in 2*L2E units
                creg[mt * 4 + r] = cn;
                float e2c = __builtin_amdgcn_exp2f(cn);          // e^2c
                float r2  = __builtin_amdgcn_rcpf((e2c + 1.0f) * (1.0f + eo));
                float hv  = (e2c - 1.0f) * r2;
                h_s[nb][(mt * 16 + quad * 4 + r) * HSTRIDE + hc] = (_Float16)hv;
            }
        }
        __syncthreads();
        buf = nb;
    }

    // ---- FC epilogue: logits = h @ Wfc + bfc ----
    if (tid < 320) {
        const int row = tid / 10, lab = tid % 10;
        float acc = bfc[lab];
        #pragma unroll 8
        for (int k = 0; k < 128; k++)
            acc += (float)h_s[buf][row * HSTRIDE + k] * Wfc[k * 10 + lab];
        out[(size_t)(rbase + row) * 10 + lab] = acc;
    }
}

extern "C" void kernel_launch(void* const* d_in, const int* in_sizes, int n_in,
                              void* d_out, int out_size, void* d_ws, size_t ws_size,
                              hipStream_t stream) {
    const float* x   = (const float*)d_in[0];
    const float* W   = (const float*)d_in[1];
    const float* b   = (const float*)d_in[2];
    const float* Wfc = (const float*)d_in[3];
    const float* bfc = (const float*)d_in[4];
    float* out = (float*)d_out;

    const int B = in_sizes[0] / (28 * 28);   // 32768
    const int blocks = B / 32;               // 1024
    lstm_r5<<<blocks, 512, 0, stream>>>(x, W, b, Wfc, bfc, out);
}

// Round 7
// 473.404 us; speedup vs baseline: 2.1116x; 2.1116x over previous
//
#include <hip/hip_runtime.h>

// SingleLSTM: B=32768, T=28, INPUT=28, HIDDEN=128, LABELS=10, fp32.
// R7 = R6 + two fixes:
//  1. RACE FIX: __syncthreads() between LDS zero-init and t=0 x staging
//     (R6's post-timing divergence: zero-fill of xs raced with the staged
//     writes, which are a cross-thread permutation of the same slots).
//  2. launch_bounds(512,3): observed caps on this toolchain are 256/w arch
//     VGPRs ((512,2)->128, (512,4)->64). 85-reg cap + 16 AGPR acc + AGPR
//     spill slack keeps TOTAL unified <=128 -> 4 waves/SIMD -> 2 resident
//     blocks/CU, out-of-phase, so activation VALU overlaps the other
//     block's MFMA phase (the per-step barrier convoy was the stall).
// Structure: fp16 datapath; 16 rows/block, 2048 blocks; wave owns 16 hidden
// cols x 4 gates (per-lane c/h update, one barrier/step); Wh resident in
// regs (64), Wx in LDS, x staged via LDS. W/bias pre-scaled by {-L2E, 2L2E,
// -L2E, -L2E}; c kept in 2*L2E units.

typedef _Float16 f16x8 __attribute__((ext_vector_type(8)));
typedef float f32x4 __attribute__((ext_vector_type(4)));

#define HSTRIDE 136    // f16 elems; 272B row
#define WXSTRIDE 40    // f16 elems; 80B row
#define L2E 1.44269504f

__global__ __launch_bounds__(512, 3)
void lstm_r7(const float* __restrict__ x,      // [B][28][28]
             const float* __restrict__ W,      // [156][512]
             const float* __restrict__ b,      // [512]
             const float* __restrict__ Wfc,    // [128][10]
             const float* __restrict__ bfc,    // [10]
             float* __restrict__ out)          // [B][10]
{
    __shared__ __align__(16) _Float16 h_s[2][16 * HSTRIDE];   // 8704 B
    __shared__ __align__(16) _Float16 xs[2][512];             // 2048 B
    __shared__ __align__(16) _Float16 wxt[512 * WXSTRIDE];    // 40960 B

    const int tid  = threadIdx.x;
    const int wave = tid >> 6;
    const int lane = tid & 63;
    const int m16  = lane & 15;
    const int quad = lane >> 4;
    const int rbase = blockIdx.x * 16;
    const int hc = wave * 16 + m16;     // this lane's hidden column

    // ---- zero h buf0 and both xs buffers ----
    for (int i = tid; i < 16 * HSTRIDE; i += 512) h_s[0][i] = (_Float16)0.0f;
    xs[0][tid] = (_Float16)0.0f;
    xs[1][tid] = (_Float16)0.0f;

    // ---- stage Wx into LDS, transposed [col][k], pre-scaled ----
    {
        const int col = tid;             // one col per thread
        const int g = col >> 7;
        const float sc = (g == 1) ? 2.0f * L2E : -L2E;
        #pragma unroll 4
        for (int k = 0; k < 32; k++)
            wxt[col * WXSTRIDE + k] = (k < 28) ? (_Float16)(sc * W[k * 512 + col])
                                               : (_Float16)0.0f;
    }

    // RACE FIX: zero-init of xs must complete before the staged (permuted)
    // writes below; R6 had no barrier here -> nondeterministic replay.
    __syncthreads();

    // ---- Wh fragments (fp16, pre-scaled), B-layout: lane holds B[k=quad*8+j][col]
    f16x8 Wh[4][4];     // [ks][gate]  -- 64 VGPRs, the big resident item
    float bias[4];
    #pragma unroll
    for (int g = 0; g < 4; g++) {
        const int col = g * 128 + wave * 16 + m16;
        const float sc = (g == 1) ? 2.0f * L2E : -L2E;
        bias[g] = sc * (b[col] + (g == 2 ? 1.0f : 0.0f));   // FORGET_BIAS folded
        #pragma unroll
        for (int ks = 0; ks < 4; ks++) {
            f16x8 h8;
            #pragma unroll
            for (int j = 0; j < 8; j++)
                h8[j] = (_Float16)(sc * W[(28 + ks * 32 + quad * 8 + j) * 512 + col]);
            Wh[ks][g] = h8;
        }
    }

    // ---- per-thread x staging slot (16 rows x 28 k = 448 elems) ----
    const bool sact = tid < 448;
    const int srow = tid / 28, sk = tid % 28;
    const int soff = (sk >> 3) * 128 + srow * 8 + (sk & 7);
    const float* xp = x + (size_t)(rbase + srow) * 784 + sk;
    if (sact) xs[0][soff] = (_Float16)(*xp);
    __syncthreads();

    float creg[4] = {0.0f, 0.0f, 0.0f, 0.0f};
    const int foff   = quad * 128 + m16 * 8;                   // xs A-frag offset
    const int wxoff0 = (wave * 16 + m16) * WXSTRIDE + quad * 8;
    const int hoff0  = m16 * HSTRIDE + quad * 8;

    int buf = 0;
    for (int t = 0; t < 28; t++) {
        const int nb = buf ^ 1;

        // stage x for t+1 (latency hidden under MFMAs); writes go to the
        // buffer read only after the NEXT barrier -> race-free
        if (t < 27 && sact) xs[nb][soff] = (_Float16)(xp[(t + 1) * 28]);

        // ---- gates for 16 rows: acc[g][r], row = quad*4+r, col = hc ----
        f32x4 acc[4];
        #pragma unroll
        for (int g = 0; g < 4; g++)
            acc[g] = (f32x4){bias[g], bias[g], bias[g], bias[g]};

        f16x8 ax = *(const f16x8*)(&xs[buf][foff]);
        #pragma unroll
        for (int g = 0; g < 4; g++) {
            f16x8 wxf = *(const f16x8*)(&wxt[g * 128 * WXSTRIDE + wxoff0]);
            acc[g] = __builtin_amdgcn_mfma_f32_16x16x32_f16(ax, wxf, acc[g], 0, 0, 0);
        }
        #pragma unroll
        for (int ks = 0; ks < 4; ks++) {
            f16x8 ah = *(const f16x8*)(&h_s[buf][hoff0 + ks * 32]);
            #pragma unroll
            for (int g = 0; g < 4; g++)
                acc[g] = __builtin_amdgcn_mfma_f32_16x16x32_f16(ah, Wh[ks][g], acc[g], 0, 0, 0);
        }

        // ---- per-lane c/h update (gates pre-scaled; c in 2*L2E units) ----
        #pragma unroll
        for (int r = 0; r < 4; r++) {
            float ei  = __builtin_amdgcn_exp2f(acc[0][r]);   // e^-i
            float e2j = __builtin_amdgcn_exp2f(acc[1][r]);   // e^2j
            float ef  = __builtin_amdgcn_exp2f(acc[2][r]);   // e^-(f+1)
            float eo  = __builtin_amdgcn_exp2f(acc[3][r]);   // e^-o
            float A  = 1.0f + ei;
            float Bv = e2j + 1.0f;
            float C  = 1.0f + ef;
            float AB = A * Bv;
            float rP = __builtin_amdgcn_rcpf(AB * C);        // 1/(A*B*C)
            float num = __builtin_fmaf(e2j, 2.0f * L2E, -2.0f * L2E);
            float cn = __builtin_fmaf(creg[r], AB * rP, num * (C * rP));
            creg[r] = cn;
            float e2c = __builtin_amdgcn_exp2f(cn);          // e^2c
            float rQ  = __builtin_amdgcn_rcpf((e2c + 1.0f) * (1.0f + eo));
            float hv  = (e2c - 1.0f) * rQ;
            h_s[nb][(quad * 4 + r) * HSTRIDE + hc] = (_Float16)hv;
        }
        __syncthreads();
        buf = nb;
    }

    // ---- FC epilogue: logits = h @ Wfc + bfc ----
    if (tid < 160) {
        const int row = tid / 10, lab = tid % 10;
        float acc = bfc[lab];
        #pragma unroll 8
        for (int k = 0; k < 128; k++)
            acc += (float)h_s[buf][row * HSTRIDE + k] * Wfc[k * 10 + lab];
        out[(size_t)(rbase + row) * 10 + lab] = acc;
    }
}

extern "C" void kernel_launch(void* const* d_in, const int* in_sizes, int n_in,
                              void* d_out, int out_size, void* d_ws, size_t ws_size,
                              hipStream_t stream) {
    const float* x   = (const float*)d_in[0];
    const float* W   = (const float*)d_in[1];
    const float* b   = (const float*)d_in[2];
    const float* Wfc = (const float*)d_in[3];
    const float* bfc = (const float*)d_in[4];
    float* out = (float*)d_out;

    const int B = in_sizes[0] / (28 * 28);   // 32768
    const int blocks = B / 16;               // 2048
    lstm_r7<<<blocks, 512, 0, stream>>>(x, W, b, Wfc, bfc, out);
}